// Round 2
// baseline (11203.771 us; speedup 1.0000x reference)
//
#include <hip/hip_runtime.h>

#define NQ 32768           // total queries = 8192 positions * K=4
#define NCODES 16384
#define ZQ_ELEMS 2097152   // 8*256*32*32
#define IDX_OFF ZQ_ELEMS
#define LOSS_OFF (ZQ_ELEMS + NQ)

// query id j = b*4096 + i*1024 + hw ; z element (j,d) at (b<<18) + (d<<12) + (i<<10) + hw

__global__ void znorm_kernel(const float* __restrict__ z, float* __restrict__ znorm) {
    int j = blockIdx.x * blockDim.x + threadIdx.x;
    int zo = ((j >> 12) << 18) + (j & 4095);
    double s = 0.0;
#pragma unroll
    for (int d = 0; d < 64; ++d) {
        float v = z[zo + (d << 12)];
        s += (double)v * (double)v;
    }
    znorm[j] = (float)s;   // any fp32 rounding of the true norm works (shift-invariance)
}

__device__ __forceinline__ unsigned long long pack_min(float f, int idx) {
    unsigned u = __float_as_uint(f);
    unsigned s = (u & 0x80000000u) ? ~u : (u | 0x80000000u); // sortable ascending
    return ((unsigned long long)s << 32) | (unsigned)idx;
}

// grid (64 query-blocks, 8 code-chunks) x 256 threads; 2 queries/thread; 128-code LDS tiles.
// Replicates numpy einsum fp32: 4 lanes (k mod 4), 16-elem groups with reversed
// muladd chain, SSE3 hadd combine; d = fl(znorm - 2*fl(dot)); ties -> lowest idx.
__global__ void argmin_kernel(const float* __restrict__ z, const float* __restrict__ emb,
                              const float* __restrict__ znorm,
                              unsigned long long* __restrict__ best) {
    __shared__ float lds_e[128 * 64];   // 32 KB, code-major
    int t = threadIdx.x;
    int jbase = blockIdx.x * 512;
    int cbase = blockIdx.y * 2048;
    int j0 = jbase + t;
    int j1 = jbase + 256 + t;
    int zo0 = ((j0 >> 12) << 18) + (j0 & 4095);
    int zo1 = ((j1 >> 12) << 18) + (j1 & 4095);

    float q0[64], q1[64];
#pragma unroll
    for (int d = 0; d < 64; ++d) {
        q0[d] = z[zo0 + (d << 12)];
        q1[d] = z[zo1 + (d << 12)];
    }
    float zn0 = znorm[j0], zn1 = znorm[j1];

    float b0 = 3.4e38f, b1 = 3.4e38f;
    int bi0 = 0, bi1 = 0;

    for (int tile = 0; tile < 16; ++tile) {
        int code0 = cbase + tile * 128;
        __syncthreads();
        const float4* src = reinterpret_cast<const float4*>(emb + (size_t)code0 * 64);
        float4* dst = reinterpret_cast<float4*>(lds_e);
#pragma unroll
        for (int r = 0; r < 8; ++r) dst[t + 256 * r] = src[t + 256 * r];
        __syncthreads();

        for (int cc = 0; cc < 128; ++cc) {
            const float4* ev = reinterpret_cast<const float4*>(lds_e + cc * 64);
            float d0, d1;
            {
#pragma clang fp contract(off)
                // SSE lane accumulators for q0 (A*) and q1 (B*)
                float A0 = 0.f, A1 = 0.f, A2 = 0.f, A3 = 0.f;
                float B0 = 0.f, B1 = 0.f, B2 = 0.f, B3 = 0.f;
#pragma unroll
                for (int b = 0; b < 4; ++b) {
                    float4 e0 = ev[b * 4 + 0];   // elems b*16 + 0..3
                    float4 e1 = ev[b * 4 + 1];   // + 4..7
                    float4 e2 = ev[b * 4 + 2];   // + 8..11
                    float4 e3 = ev[b * 4 + 3];   // + 12..15
                    int o = b * 16;
                    // vacc = a0*b0 + (a1*b1 + (a2*b2 + (a3*b3 + vacc)))  [reversed chain]
                    A0 = e0.x * q0[o + 0] + (e1.x * q0[o + 4] + (e2.x * q0[o + 8]  + (e3.x * q0[o + 12] + A0)));
                    A1 = e0.y * q0[o + 1] + (e1.y * q0[o + 5] + (e2.y * q0[o + 9]  + (e3.y * q0[o + 13] + A1)));
                    A2 = e0.z * q0[o + 2] + (e1.z * q0[o + 6] + (e2.z * q0[o + 10] + (e3.z * q0[o + 14] + A2)));
                    A3 = e0.w * q0[o + 3] + (e1.w * q0[o + 7] + (e2.w * q0[o + 11] + (e3.w * q0[o + 15] + A3)));
                    B0 = e0.x * q1[o + 0] + (e1.x * q1[o + 4] + (e2.x * q1[o + 8]  + (e3.x * q1[o + 12] + B0)));
                    B1 = e0.y * q1[o + 1] + (e1.y * q1[o + 5] + (e2.y * q1[o + 9]  + (e3.y * q1[o + 13] + B1)));
                    B2 = e0.z * q1[o + 2] + (e1.z * q1[o + 6] + (e2.z * q1[o + 10] + (e3.z * q1[o + 14] + B2)));
                    B3 = e0.w * q1[o + 3] + (e1.w * q1[o + 7] + (e2.w * q1[o + 11] + (e3.w * q1[o + 15] + B3)));
                }
                float dot0 = (A0 + A1) + (A2 + A3);   // SSE3 hadd order
                float dot1 = (B0 + B1) + (B2 + B3);
                d0 = zn0 - (dot0 + dot0);             // fl(znorm - 2*dot), 2*dot exact
                d1 = zn1 - (dot1 + dot1);
            }
            int m = code0 + cc;
            if (d0 < b0) { b0 = d0; bi0 = m; }
            if (d1 < b1) { b1 = d1; bi1 = m; }
        }
    }
    atomicMin(&best[j0], pack_min(b0, bi0));
    atomicMin(&best[j1], pack_min(b1, bi1));
}

__global__ void finalize_kernel(const float* __restrict__ z, const float* __restrict__ emb,
                                const unsigned long long* __restrict__ best,
                                float* __restrict__ out) {
    __shared__ float red[256];
    int t = threadIdx.x;
    int j = blockIdx.x * 256 + t;
    int idx = (int)(unsigned)(best[j] & 0xFFFFFFFFull);
    out[IDX_OFF + j] = (float)idx;

    size_t zo = ((size_t)(j >> 12) << 18) + (size_t)(j & 4095);
    const float* e = emb + (size_t)idx * 64;
    float ls = 0.f;
#pragma unroll
    for (int d = 0; d < 64; ++d) {
        float ev = e[d];
        float zv = z[zo + ((size_t)d << 12)];
        float r = ev - zv;
        ls += r * r;
        out[zo + ((size_t)d << 12)] = ev;  // z_q straight-through == emb[idx]
    }
    red[t] = ls;
    __syncthreads();
    for (int off = 128; off > 0; off >>= 1) {
        if (t < off) red[t] += red[t + off];
        __syncthreads();
    }
    if (t == 0) atomicAdd(&out[LOSS_OFF], red[0] * (1.25f / 2097152.f));
}

extern "C" void kernel_launch(void* const* d_in, const int* in_sizes, int n_in,
                              void* d_out, int out_size, void* d_ws, size_t ws_size,
                              hipStream_t stream) {
    const float* z = (const float*)d_in[0];
    const float* emb = (const float*)d_in[1];
    float* out = (float*)d_out;

    unsigned long long* best = (unsigned long long*)d_ws;          // 256 KB
    float* znorm = (float*)((char*)d_ws + (size_t)NQ * 8);         // +128 KB

    hipMemsetAsync(d_ws, 0xFF, (size_t)NQ * 8, stream);
    hipMemsetAsync((char*)d_out + (size_t)LOSS_OFF * 4, 0, 4, stream);

    znorm_kernel<<<NQ / 256, 256, 0, stream>>>(z, znorm);
    argmin_kernel<<<dim3(64, 8), 256, 0, stream>>>(z, emb, znorm, best);
    finalize_kernel<<<NQ / 256, 256, 0, stream>>>(z, emb, best, out);
}

// Round 3
// 1473.117 us; speedup vs baseline: 7.6055x; 7.6055x over previous
//
#include <hip/hip_runtime.h>

#define NQ 32768           // total queries = 8192 positions * K=4
#define NCODES 16384
#define ZQ_ELEMS 2097152   // 8*256*32*32
#define IDX_OFF ZQ_ELEMS
#define LOSS_OFF (ZQ_ELEMS + NQ)

// query id j = b*4096 + i*1024 + hw ; z element (j,d) at (b<<18) + (d<<12) + (i<<10) + hw

__global__ void znorm_kernel(const float* __restrict__ z, float* __restrict__ znorm) {
    int j = blockIdx.x * blockDim.x + threadIdx.x;
    int zo = ((j >> 12) << 18) + (j & 4095);
    double s = 0.0;
#pragma unroll
    for (int d = 0; d < 64; ++d) {
        float v = z[zo + (d << 12)];
        s += (double)v * (double)v;
    }
    znorm[j] = (float)s;   // any fp32 rounding of the true norm works (shift-invariance)
}

__device__ __forceinline__ unsigned long long pack_min(float f, int idx) {
    unsigned u = __float_as_uint(f);
    unsigned s = (u & 0x80000000u) ? ~u : (u | 0x80000000u); // sortable ascending
    return ((unsigned long long)s << 32) | (unsigned)idx;
}

__device__ __forceinline__ float4 loadq(const float* __restrict__ z, int zo, int i) {
    return make_float4(z[zo + ((4 * i + 0) << 12)], z[zo + ((4 * i + 1) << 12)],
                       z[zo + ((4 * i + 2) << 12)], z[zo + ((4 * i + 3) << 12)]);
}

// lane l accumulator gets component l of each group float4; chain g=0 outermost:
// A = e0*g0 + (e1*g1 + (e2*g2 + (e3*g3 + A)))
#define GROUP(g0, g1, g2, g3, A0, A1, A2, A3)                                   \
    A0 = e0.x * g0.x + (e1.x * g1.x + (e2.x * g2.x + (e3.x * g3.x + A0)));      \
    A1 = e0.y * g0.y + (e1.y * g1.y + (e2.y * g2.y + (e3.y * g3.y + A1)));      \
    A2 = e0.z * g0.z + (e1.z * g1.z + (e2.z * g2.z + (e3.z * g3.z + A2)));      \
    A3 = e0.w * g0.w + (e1.w * g1.w + (e2.w * g2.w + (e3.w * g3.w + A3)));

// grid (64 query-blocks, 8 code-chunks) x 256 threads; 2 queries/thread; 128-code LDS tiles.
// Replicates numpy einsum fp32: 4 SSE lanes, 16-elem groups with reversed muladd
// chain, hadd combine; d = fl(znorm - 2*fl(dot)); ties -> lowest idx via packed u64.
__global__ void __launch_bounds__(256, 2)
argmin_kernel(const float* __restrict__ z, const float* __restrict__ emb,
              const float* __restrict__ znorm,
              unsigned long long* __restrict__ best) {
    __shared__ float lds_e[128 * 64];   // 32 KB, code-major
    int t = threadIdx.x;
    int jbase = blockIdx.x * 512;
    int cbase = blockIdx.y * 2048;
    int j0 = jbase + t;
    int j1 = jbase + 256 + t;
    int zo0 = ((j0 >> 12) << 18) + (j0 & 4095);
    int zo1 = ((j1 >> 12) << 18) + (j1 & 4095);

    // 16 named float4 per query -> guaranteed VGPR residency (no alloca)
    float4 qa0 = loadq(z, zo0, 0),  qa1 = loadq(z, zo0, 1),  qa2 = loadq(z, zo0, 2),  qa3 = loadq(z, zo0, 3);
    float4 qa4 = loadq(z, zo0, 4),  qa5 = loadq(z, zo0, 5),  qa6 = loadq(z, zo0, 6),  qa7 = loadq(z, zo0, 7);
    float4 qa8 = loadq(z, zo0, 8),  qa9 = loadq(z, zo0, 9),  qa10 = loadq(z, zo0, 10), qa11 = loadq(z, zo0, 11);
    float4 qa12 = loadq(z, zo0, 12), qa13 = loadq(z, zo0, 13), qa14 = loadq(z, zo0, 14), qa15 = loadq(z, zo0, 15);
    float4 qb0 = loadq(z, zo1, 0),  qb1 = loadq(z, zo1, 1),  qb2 = loadq(z, zo1, 2),  qb3 = loadq(z, zo1, 3);
    float4 qb4 = loadq(z, zo1, 4),  qb5 = loadq(z, zo1, 5),  qb6 = loadq(z, zo1, 6),  qb7 = loadq(z, zo1, 7);
    float4 qb8 = loadq(z, zo1, 8),  qb9 = loadq(z, zo1, 9),  qb10 = loadq(z, zo1, 10), qb11 = loadq(z, zo1, 11);
    float4 qb12 = loadq(z, zo1, 12), qb13 = loadq(z, zo1, 13), qb14 = loadq(z, zo1, 14), qb15 = loadq(z, zo1, 15);

    float zn0 = znorm[j0], zn1 = znorm[j1];

    float b0 = 3.4e38f, b1 = 3.4e38f;
    int bi0 = 0, bi1 = 0;

    for (int tile = 0; tile < 16; ++tile) {
        int code0 = cbase + tile * 128;
        __syncthreads();
        const float4* src = reinterpret_cast<const float4*>(emb + (size_t)code0 * 64);
        float4* dst = reinterpret_cast<float4*>(lds_e);
#pragma unroll
        for (int r = 0; r < 8; ++r) dst[t + 256 * r] = src[t + 256 * r];
        __syncthreads();

        for (int cc = 0; cc < 128; ++cc) {
            const float4* ev = reinterpret_cast<const float4*>(lds_e + cc * 64);
            float d0, d1;
            {
#pragma clang fp contract(off)
                float sA0 = 0.f, sA1 = 0.f, sA2 = 0.f, sA3 = 0.f;
                float sB0 = 0.f, sB1 = 0.f, sB2 = 0.f, sB3 = 0.f;
                float4 e0, e1, e2, e3;
                // b=0 : elements 0..15
                e0 = ev[0];  e1 = ev[1];  e2 = ev[2];  e3 = ev[3];
                GROUP(qa0, qa1, qa2, qa3, sA0, sA1, sA2, sA3)
                GROUP(qb0, qb1, qb2, qb3, sB0, sB1, sB2, sB3)
                // b=1 : elements 16..31
                e0 = ev[4];  e1 = ev[5];  e2 = ev[6];  e3 = ev[7];
                GROUP(qa4, qa5, qa6, qa7, sA0, sA1, sA2, sA3)
                GROUP(qb4, qb5, qb6, qb7, sB0, sB1, sB2, sB3)
                // b=2 : elements 32..47
                e0 = ev[8];  e1 = ev[9];  e2 = ev[10]; e3 = ev[11];
                GROUP(qa8, qa9, qa10, qa11, sA0, sA1, sA2, sA3)
                GROUP(qb8, qb9, qb10, qb11, sB0, sB1, sB2, sB3)
                // b=3 : elements 48..63
                e0 = ev[12]; e1 = ev[13]; e2 = ev[14]; e3 = ev[15];
                GROUP(qa12, qa13, qa14, qa15, sA0, sA1, sA2, sA3)
                GROUP(qb12, qb13, qb14, qb15, sB0, sB1, sB2, sB3)

                float dot0 = (sA0 + sA1) + (sA2 + sA3);   // SSE3 hadd order
                float dot1 = (sB0 + sB1) + (sB2 + sB3);
                d0 = zn0 - (dot0 + dot0);                 // fl(znorm - 2*dot)
                d1 = zn1 - (dot1 + dot1);
            }
            int m = code0 + cc;
            if (d0 < b0) { b0 = d0; bi0 = m; }
            if (d1 < b1) { b1 = d1; bi1 = m; }
        }
    }
    atomicMin(&best[j0], pack_min(b0, bi0));
    atomicMin(&best[j1], pack_min(b1, bi1));
}

__global__ void finalize_kernel(const float* __restrict__ z, const float* __restrict__ emb,
                                const unsigned long long* __restrict__ best,
                                float* __restrict__ out) {
    __shared__ float red[256];
    int t = threadIdx.x;
    int j = blockIdx.x * 256 + t;
    int idx = (int)(unsigned)(best[j] & 0xFFFFFFFFull);
    out[IDX_OFF + j] = (float)idx;

    size_t zo = ((size_t)(j >> 12) << 18) + (size_t)(j & 4095);
    const float* e = emb + (size_t)idx * 64;
    float ls = 0.f;
#pragma unroll
    for (int d = 0; d < 64; ++d) {
        float ev = e[d];
        float zv = z[zo + ((size_t)d << 12)];
        float r = ev - zv;
        ls += r * r;
        out[zo + ((size_t)d << 12)] = ev;  // z_q straight-through == emb[idx]
    }
    red[t] = ls;
    __syncthreads();
    for (int off = 128; off > 0; off >>= 1) {
        if (t < off) red[t] += red[t + off];
        __syncthreads();
    }
    if (t == 0) atomicAdd(&out[LOSS_OFF], red[0] * (1.25f / 2097152.f));
}

extern "C" void kernel_launch(void* const* d_in, const int* in_sizes, int n_in,
                              void* d_out, int out_size, void* d_ws, size_t ws_size,
                              hipStream_t stream) {
    const float* z = (const float*)d_in[0];
    const float* emb = (const float*)d_in[1];
    float* out = (float*)d_out;

    unsigned long long* best = (unsigned long long*)d_ws;          // 256 KB
    float* znorm = (float*)((char*)d_ws + (size_t)NQ * 8);         // +128 KB

    hipMemsetAsync(d_ws, 0xFF, (size_t)NQ * 8, stream);
    hipMemsetAsync((char*)d_out + (size_t)LOSS_OFF * 4, 0, 4, stream);

    znorm_kernel<<<NQ / 256, 256, 0, stream>>>(z, znorm);
    argmin_kernel<<<dim3(64, 8), 256, 0, stream>>>(z, emb, znorm, best);
    finalize_kernel<<<NQ / 256, 256, 0, stream>>>(z, emb, best, out);
}